// Round 1
// baseline (155.896 us; speedup 1.0000x reference)
//
#include <hip/hip_runtime.h>

// 4-bit comparator: A,B are (N,4) float32 of exact 0.0/1.0 values, col 0 = MSB.
// Reference's soft-boolean algebra reduces exactly to integer compare since all
// OR-terms are mutually exclusive. Outputs: a_gt_b (N floats) then a_eq_b (N floats).

__global__ __launch_bounds__(256) void cmp4_kernel(const float4* __restrict__ A,
                                                   const float4* __restrict__ B,
                                                   float* __restrict__ out_gt,
                                                   float* __restrict__ out_eq,
                                                   int n) {
    int i = blockIdx.x * blockDim.x + threadIdx.x;
    if (i >= n) return;
    float4 a = A[i];
    float4 b = B[i];
    // values are exactly 0.0f or 1.0f; != 0 test packs the bit
    int ai = ((a.x != 0.0f) << 3) | ((a.y != 0.0f) << 2) | ((a.z != 0.0f) << 1) | (a.w != 0.0f);
    int bi = ((b.x != 0.0f) << 3) | ((b.y != 0.0f) << 2) | ((b.z != 0.0f) << 1) | (b.w != 0.0f);
    out_gt[i] = (ai > bi) ? 1.0f : 0.0f;
    out_eq[i] = (ai == bi) ? 1.0f : 0.0f;
}

extern "C" void kernel_launch(void* const* d_in, const int* in_sizes, int n_in,
                              void* d_out, int out_size, void* d_ws, size_t ws_size,
                              hipStream_t stream) {
    const float4* A = (const float4*)d_in[0];
    const float4* B = (const float4*)d_in[1];
    float* out = (float*)d_out;
    int n = in_sizes[0] / 4;          // rows
    float* out_gt = out;              // first output, N elements
    float* out_eq = out + n;          // second output, N elements
    int block = 256;
    int grid = (n + block - 1) / block;
    cmp4_kernel<<<grid, block, 0, stream>>>(A, B, out_gt, out_eq, n);
}